// Round 5
// baseline (396.794 us; speedup 1.0000x reference)
//
#include <hip/hip_runtime.h>
#include <hip/hip_bf16.h>
#include <stdint.h>

#define B_ 256
#define T_ 512
#define C_ 14
#define CO_ 32
#define H_ 128
#define G_ 512   // 4*H

__device__ __forceinline__ float sigm_fast(float x) {
  float e = __expf(-x);
  return __builtin_amdgcn_rcpf(1.f + e);
}
__device__ __forceinline__ float tanh_fast(float x) {
  float e = __expf(2.f * x);               // inf-safe: x>>0 -> 1, x<<0 -> -1
  return 1.f - 2.f * __builtin_amdgcn_rcpf(1.f + e);
}

// ---------------- Kernel 0: fast-path flag ---------------------------------
// mem = o*tanh(syn) - reset*thr is strictly < 1 (sigmoid<1, |tanh|<1).
// Spike needs mem - thr > 0, impossible when thr >= 1 -> layer-1 spikes are
// identically zero for ANY inputs when thr1 >= 1. Guard at runtime.
__global__ void k_flag(const float* __restrict__ thr1, int* __restrict__ flag) {
  if (threadIdx.x == 0) flag[0] = (thr1[0] >= 1.0f) ? 1 : 0;
}

// ---------------- Kernel 1: conv over time + Leaky spike (fallback) --------
__global__ __launch_bounds__(256) void k_conv_spike(
    const int* __restrict__ flag, const float* __restrict__ x,
    const float* __restrict__ cw, const float* __restrict__ cb,
    unsigned int* __restrict__ cur1) {
  if (flag[0]) return;
  __shared__ float w_s[CO_ * C_ * 3];
  __shared__ float b_s[CO_];
  for (int i = threadIdx.x; i < CO_ * C_ * 3; i += blockDim.x) w_s[i] = cw[i];
  if (threadIdx.x < CO_) b_s[threadIdx.x] = cb[threadIdx.x];
  __syncthreads();
  int idx = blockIdx.x * blockDim.x + threadIdx.x;  // b*T + t
  if (idx >= B_ * T_) return;
  int b = idx / T_, t = idx % T_;
  float xin[3][C_];
#pragma unroll
  for (int k = 0; k < 3; ++k) {
    int tt = t + k - 1;
    if (tt < 0 || tt >= T_) {
#pragma unroll
      for (int c = 0; c < C_; ++c) xin[k][c] = 0.f;
    } else {
      const float* p = x + ((size_t)b * T_ + tt) * C_;
#pragma unroll
      for (int c = 0; c < C_; ++c) xin[k][c] = p[c];
    }
  }
  unsigned int bits = 0u;
  for (int oc = 0; oc < CO_; ++oc) {
    float s = b_s[oc];
    const float* wr = &w_s[oc * C_ * 3];
#pragma unroll
    for (int ic = 0; ic < C_; ++ic)
#pragma unroll
      for (int k = 0; k < 3; ++k) s = fmaf(xin[k][ic], wr[ic * 3 + k], s);
    if (s - 1.0f > 0.f) bits |= (1u << oc);
  }
  cur1[idx] = bits;
}

// ---------------- Kernel 2: honest SLSTM layer 1 (fallback only) -----------
__global__ __launch_bounds__(512, 2) void k_slstm1(
    const int* __restrict__ flag, const unsigned int* __restrict__ cur1,
    const float* __restrict__ w_ih, const float* __restrict__ w_hh,
    const float* __restrict__ b_ih, const float* __restrict__ b_hh,
    const float* __restrict__ thr_p, unsigned long long* __restrict__ spk_bits,
    unsigned int* __restrict__ count) {
  if (flag[0]) return;  // fast path: spikes provably zero; count stays 0
  const int g = threadIdx.x;
  const int t0 = blockIdx.x * 2;
  const float thr = thr_p[0];
  float wih[32], whh[H_];
#pragma unroll
  for (int k = 0; k < 32; ++k) wih[k] = w_ih[g * 32 + k];
#pragma unroll
  for (int k = 0; k < H_; ++k) whh[k] = w_hh[g * H_ + k];
  const float bias = b_ih[g] + b_hh[g];
  __shared__ float mem_s[2][H_];
  __shared__ float gate_s[2][G_];
  float syn = 0.f;
  int cnt = 0;
  if (g < 256) mem_s[g >> 7][g & 127] = 0.f;
  __syncthreads();
  for (int b = 0; b < B_; ++b) {
    unsigned int bits0 = cur1[b * T_ + t0];
    unsigned int bits1 = cur1[b * T_ + t0 + 1];
    float s0 = bias, s1 = bias;
#pragma unroll
    for (int k = 0; k < 32; ++k) {
      s0 += ((bits0 >> k) & 1u) ? wih[k] : 0.f;
      s1 += ((bits1 >> k) & 1u) ? wih[k] : 0.f;
    }
#pragma unroll
    for (int k = 0; k < H_; ++k) {
      s0 = fmaf(whh[k], mem_s[0][k], s0);
      s1 = fmaf(whh[k], mem_s[1][k], s1);
    }
    gate_s[0][g] = s0;
    gate_s[1][g] = s1;
    __syncthreads();
    if (g < 256) {
      const int r = g >> 7, h = g & 127;
      float gi = gate_s[r][h];
      float gf = gate_s[r][h + 128];
      float gg = gate_s[r][h + 256];
      float go = gate_s[r][h + 384];
      float ii = 1.f / (1.f + expf(-gi));
      float ff = 1.f / (1.f + expf(-gf));
      float gt = tanhf(gg);
      float oo = 1.f / (1.f + expf(-go));
      float memp = mem_s[r][h];
      float rst = (memp - thr > 0.f) ? thr : 0.f;
      syn = ff * syn + ii * gt;
      float mm = oo * tanhf(syn) - rst;
      mem_s[r][h] = mm;
      bool spk = (mm - thr) > 0.f;
      cnt += spk ? 1 : 0;
      unsigned long long m = __ballot(spk);
      if ((g & 63) == 0)
        spk_bits[((size_t)b * T_ + t0 + r) * 2 + ((h >> 6) & 1)] = m;
    }
    __syncthreads();
  }
  if (g < 256) atomicAdd(&count[g & 127], (unsigned int)cnt);
}

// ---------------- Kernel 3: BN params from spike counts --------------------
// Runs in BOTH paths (fast path: count==0 -> c = beta exactly).
__global__ void k_bnprep(const unsigned int* __restrict__ count,
                         const float* __restrict__ gamma,
                         const float* __restrict__ beta,
                         float* __restrict__ a, float* __restrict__ c) {
  int h = threadIdx.x;
  if (h >= H_) return;
  const float inv_n = 1.f / (float)(B_ * T_);
  float mu = (float)count[h] * inv_n;
  float var = mu * (1.f - mu);
  float ai = gamma[h] / sqrtf(var + 1e-5f);
  a[h] = ai;
  c[h] = beta[h] - mu * ai;
}

// ---------------- Kernel 4: fold BN into layer-2 weights (cg both paths) ---
__global__ void k_fold(const int* __restrict__ flag,
                       const float* __restrict__ w_ih2,
                       const float* __restrict__ b_ih2,
                       const float* __restrict__ b_hh2,
                       const float* __restrict__ a, const float* __restrict__ c,
                       float* __restrict__ W2p, float* __restrict__ cg) {
  int gi = blockIdx.x * blockDim.x + threadIdx.x;  // 0..511
  if (gi >= G_) return;
  const int fl = flag[0];
  float s = b_ih2[gi] + b_hh2[gi];
  for (int h = 0; h < H_; ++h) {
    float w = w_ih2[gi * H_ + h];
    if (!fl) W2p[h * G_ + gi] = w * a[h];  // fallback-only matrix
    s = fmaf(w, c[h], s);
  }
  cg[gi] = s;
}

// ---------------- Kernel 5: honest SLSTM layer 2 (fallback only) -----------
__global__ __launch_bounds__(512, 2) void k_slstm2(
    const int* __restrict__ flag, const unsigned long long* __restrict__ spk_bits,
    const float* __restrict__ w_hh, const float* __restrict__ W2p,
    const float* __restrict__ cg, const float* __restrict__ thr_p,
    float* __restrict__ acc_out) {
  if (flag[0]) return;  // fast path handled by k_traj
  const int g = threadIdx.x;
  const int t0 = blockIdx.x * 2;
  const float thr = thr_p[0];
  float whh[H_];
#pragma unroll
  for (int k = 0; k < H_; ++k) whh[k] = w_hh[g * H_ + k];
  const float bias = cg[g];
  __shared__ float mem_s[2][H_];
  __shared__ float gate_s[2][G_];
  float syn = 0.f, accv = 0.f;
  if (g < 256) mem_s[g >> 7][g & 127] = 0.f;
  __syncthreads();
  for (int b = 0; b < B_; ++b) {
    unsigned long long m00 = spk_bits[((size_t)b * T_ + t0) * 2 + 0];
    unsigned long long m01 = spk_bits[((size_t)b * T_ + t0) * 2 + 1];
    unsigned long long m10 = spk_bits[((size_t)b * T_ + t0 + 1) * 2 + 0];
    unsigned long long m11 = spk_bits[((size_t)b * T_ + t0 + 1) * 2 + 1];
    float s0 = bias, s1 = bias;
    while (m00) { int h = __ffsll(m00) - 1; m00 &= m00 - 1; s0 += W2p[h * G_ + g]; }
    while (m01) { int h = __ffsll(m01) - 1; m01 &= m01 - 1; s0 += W2p[(h + 64) * G_ + g]; }
    while (m10) { int h = __ffsll(m10) - 1; m10 &= m10 - 1; s1 += W2p[h * G_ + g]; }
    while (m11) { int h = __ffsll(m11) - 1; m11 &= m11 - 1; s1 += W2p[(h + 64) * G_ + g]; }
#pragma unroll
    for (int k = 0; k < H_; ++k) {
      s0 = fmaf(whh[k], mem_s[0][k], s0);
      s1 = fmaf(whh[k], mem_s[1][k], s1);
    }
    gate_s[0][g] = s0;
    gate_s[1][g] = s1;
    __syncthreads();
    if (g < 256) {
      const int r = g >> 7, h = g & 127;
      float gi = gate_s[r][h];
      float gf = gate_s[r][h + 128];
      float gg = gate_s[r][h + 256];
      float go = gate_s[r][h + 384];
      float ii = 1.f / (1.f + expf(-gi));
      float ff = 1.f / (1.f + expf(-gf));
      float gt = tanhf(gg);
      float oo = 1.f / (1.f + expf(-go));
      float memp = mem_s[r][h];
      float rst = (memp - thr > 0.f) ? thr : 0.f;
      syn = ff * syn + ii * gt;
      float mm = oo * tanhf(syn) - rst;
      mem_s[r][h] = mm;
      accv += mm;
    }
    __syncthreads();
  }
  if (g < 256) acc_out[(size_t)(t0 + (g >> 7)) * H_ + (g & 127)] = accv;
}

// ---------------- Kernel 5b: FAST layer 2 — single shared trajectory -------
// thr1>=1 -> layer-2 input = beta every row/step -> ONE 256-step trajectory.
// 1024 threads: thread i owns gate g=i>>1, half hf=i&1 -> 64 weights in 16
// NAMED float4 values. amdgpu_waves_per_eu(4,4) pins the VGPR budget at 128
// (we launch ONE block; occupancy is irrelevant, only the reg cap matters).
// Per-iteration asm keep-alives forbid rematerializing the weight loads.
#define PIN4(v) asm volatile("" : "+v"(v.x), "+v"(v.y), "+v"(v.z), "+v"(v.w))

#define DOT4(W, P, OFF)                                                  \
  {                                                                      \
    float4 m_ = *(const float4*)&(P)[(OFF)];                             \
    a0 = fmaf(W.x, m_.x, a0); a1 = fmaf(W.y, m_.y, a1);                  \
    a2 = fmaf(W.z, m_.z, a2); a3 = fmaf(W.w, m_.w, a3);                  \
  }

__global__ __launch_bounds__(1024)
__attribute__((amdgpu_waves_per_eu(4, 4))) void k_traj(
    const int* __restrict__ flag, const float* __restrict__ w_hh,
    const float* __restrict__ cg, const float* __restrict__ thr_p,
    const float* __restrict__ fc_w, const float* __restrict__ fc_b,
    float* __restrict__ out) {
  if (!flag[0]) return;
  const int i = threadIdx.x;
  const int g = i >> 1;
  const int hf = i & 1;
  const float thr = thr_p[0];

  const float* wr = w_hh + (size_t)g * H_ + hf * 64;
  float4 w0 = *(const float4*)(wr);
  float4 w1 = *(const float4*)(wr + 4);
  float4 w2 = *(const float4*)(wr + 8);
  float4 w3 = *(const float4*)(wr + 12);
  float4 w4 = *(const float4*)(wr + 16);
  float4 w5 = *(const float4*)(wr + 20);
  float4 w6 = *(const float4*)(wr + 24);
  float4 w7 = *(const float4*)(wr + 28);
  float4 w8 = *(const float4*)(wr + 32);
  float4 w9 = *(const float4*)(wr + 36);
  float4 wA = *(const float4*)(wr + 40);
  float4 wB = *(const float4*)(wr + 44);
  float4 wC = *(const float4*)(wr + 48);
  float4 wD = *(const float4*)(wr + 52);
  float4 wE = *(const float4*)(wr + 56);
  float4 wF = *(const float4*)(wr + 60);
  const float bias = hf ? 0.f : cg[g];

  __shared__ float mem_s[H_];
  __shared__ float gate_s[G_];
  __shared__ float red_s[H_ + 8];
  float syn = 0.f, accm = 0.f;
  if (i < H_) mem_s[i] = 0.f;
  __syncthreads();

  const float* memh = &mem_s[hf << 6];
  for (int b = 0; b < B_; ++b) {
    // keep the 64 weight floats pinned in VGPRs across the loop back-edge
    PIN4(w0); PIN4(w1); PIN4(w2); PIN4(w3);
    PIN4(w4); PIN4(w5); PIN4(w6); PIN4(w7);
    PIN4(w8); PIN4(w9); PIN4(wA); PIN4(wB);
    PIN4(wC); PIN4(wD); PIN4(wE); PIN4(wF);
    // phase 1: all 1024 threads, half-gate dot products
    float a0 = bias, a1 = 0.f, a2 = 0.f, a3 = 0.f;
    DOT4(w0, memh, 0)  DOT4(w1, memh, 4)  DOT4(w2, memh, 8)  DOT4(w3, memh, 12)
    DOT4(w4, memh, 16) DOT4(w5, memh, 20) DOT4(w6, memh, 24) DOT4(w7, memh, 28)
    DOT4(w8, memh, 32) DOT4(w9, memh, 36) DOT4(wA, memh, 40) DOT4(wB, memh, 44)
    DOT4(wC, memh, 48) DOT4(wD, memh, 52) DOT4(wE, memh, 56) DOT4(wF, memh, 60)
    float s = (a0 + a1) + (a2 + a3);
    s += __shfl_xor(s, 1);
    if (!hf) gate_s[g] = s;
    __syncthreads();
    // phase 2: 512 threads, one transcendental each; quad-shfl gather
    if (i < 512) {
      const int h = i >> 2, r = i & 3;
      float xg = gate_s[h + (r << 7)];
      float act = (r == 2) ? tanh_fast(xg) : sigm_fast(xg);
      const int base = (i & 63) & ~3;
      float af = __shfl(act, base + 1);
      float ag = __shfl(act, base + 2);
      float ao = __shfl(act, base + 3);
      if (r == 0) {
        float memp = mem_s[h];
        float rst = (memp - thr > 0.f) ? thr : 0.f;  // honest (thr2 runtime)
        syn = af * syn + act * ag;
        float mm = ao * tanh_fast(syn) - rst;
        mem_s[h] = mm;
        accm += mm;
      }
    }
    __syncthreads();
  }
  // mean over steps -> FC (8 outputs) -> broadcast to all 512 rows
  if (i < 512 && (i & 3) == 0) red_s[i >> 2] = accm * (1.f / 256.f);
  __syncthreads();
  if (i < 8) {
    float s = fc_b[i];
    const float* fw = fc_w + i * H_;
    for (int h = 0; h < H_; ++h) s = fmaf(red_s[h], fw[h], s);
    red_s[H_ + i] = s;
  }
  __syncthreads();
  for (int idx = i; idx < T_ * 8; idx += 1024) out[idx] = red_s[H_ + (idx & 7)];
}

// ---------------- Kernel 6: final mean + FC (fallback only) ----------------
__global__ void k_out(const int* __restrict__ flag, const float* __restrict__ accv,
                      const float* __restrict__ fc_w,
                      const float* __restrict__ fc_b, float* __restrict__ out) {
  if (flag[0]) return;
  int idx = blockIdx.x * blockDim.x + threadIdx.x;  // t*8+n
  if (idx >= T_ * 8) return;
  int t = idx >> 3, n = idx & 7;
  float s = fc_b[n];
  for (int h = 0; h < H_; ++h)
    s = fmaf(accv[t * H_ + h] * (1.f / 256.f), fc_w[n * H_ + h], s);
  out[idx] = s;
}

extern "C" void kernel_launch(void* const* d_in, const int* in_sizes, int n_in,
                              void* d_out, int out_size, void* d_ws, size_t ws_size,
                              hipStream_t stream) {
  const float* x       = (const float*)d_in[0];
  const float* conv_w  = (const float*)d_in[1];
  const float* conv_b  = (const float*)d_in[2];
  const float* w_ih1   = (const float*)d_in[3];
  const float* w_hh1   = (const float*)d_in[4];
  const float* b_ih1   = (const float*)d_in[5];
  const float* b_hh1   = (const float*)d_in[6];
  const float* thr1    = (const float*)d_in[7];
  const float* w_ih2   = (const float*)d_in[8];
  const float* w_hh2   = (const float*)d_in[9];
  const float* b_ih2   = (const float*)d_in[10];
  const float* b_hh2   = (const float*)d_in[11];
  const float* thr2    = (const float*)d_in[12];
  const float* bn_g    = (const float*)d_in[13];
  const float* bn_b    = (const float*)d_in[14];
  const float* fc_w    = (const float*)d_in[15];
  const float* fc_b    = (const float*)d_in[16];
  float* out = (float*)d_out;

  char* ws = (char*)d_ws;
  unsigned int* cur1       = (unsigned int*)(ws);                    // 512 KB
  unsigned long long* spk  = (unsigned long long*)(ws + (512 << 10));// 2 MB
  unsigned int* count      = (unsigned int*)(ws + (2560 << 10));     // 512 B
  float* a                 = (float*)(ws + (2561 << 10));            // 512 B
  float* c                 = (float*)(ws + (2562 << 10));            // 512 B
  float* cg                = (float*)(ws + (2563 << 10));            // 2 KB
  float* W2p               = (float*)(ws + (2566 << 10));            // 256 KB
  float* accv              = (float*)(ws + (2822 << 10));            // 256 KB
  int* flag                = (int*)(ws + (3078 << 10));              // 4 B

  hipMemsetAsync(count, 0, H_ * sizeof(unsigned int), stream);
  k_flag<<<1, 64, 0, stream>>>(thr1, flag);
  k_conv_spike<<<(B_ * T_ + 255) / 256, 256, 0, stream>>>(flag, x, conv_w, conv_b, cur1);
  k_slstm1<<<T_ / 2, 512, 0, stream>>>(flag, cur1, w_ih1, w_hh1, b_ih1, b_hh1,
                                       thr1, spk, count);
  k_bnprep<<<1, 128, 0, stream>>>(count, bn_g, bn_b, a, c);
  k_fold<<<1, 512, 0, stream>>>(flag, w_ih2, b_ih2, b_hh2, a, c, W2p, cg);
  k_slstm2<<<T_ / 2, 512, 0, stream>>>(flag, spk, w_hh2, W2p, cg, thr2, accv);
  k_traj<<<1, 1024, 0, stream>>>(flag, w_hh2, cg, thr2, fc_w, fc_b, out);
  k_out<<<(T_ * 8 + 255) / 256, 256, 0, stream>>>(flag, accv, fc_w, fc_b, out);
}

// Round 6
// 372.779 us; speedup vs baseline: 1.0644x; 1.0644x over previous
//
#include <hip/hip_runtime.h>
#include <hip/hip_bf16.h>
#include <stdint.h>

#define B_ 256
#define T_ 512
#define C_ 14
#define CO_ 32
#define H_ 128
#define G_ 512   // 4*H

__device__ __forceinline__ float sigm_fast(float x) {
  float e = __expf(-x);
  return __builtin_amdgcn_rcpf(1.f + e);
}
__device__ __forceinline__ float tanh_fast(float x) {
  float e = __expf(2.f * x);               // inf-safe: x>>0 -> 1, x<<0 -> -1
  return 1.f - 2.f * __builtin_amdgcn_rcpf(1.f + e);
}

// ---------------- Kernel 0: fast-path flag ---------------------------------
// mem = o*tanh(syn) - reset*thr is strictly < 1 (sigmoid<1, |tanh|<1).
// Spike needs mem - thr > 0, impossible when thr >= 1 -> layer-1 spikes are
// identically zero for ANY inputs when thr1 >= 1. Guard at runtime.
__global__ void k_flag(const float* __restrict__ thr1, int* __restrict__ flag) {
  if (threadIdx.x == 0) flag[0] = (thr1[0] >= 1.0f) ? 1 : 0;
}

// ---------------- Kernel 1: conv over time + Leaky spike (fallback) --------
__global__ __launch_bounds__(256) void k_conv_spike(
    const int* __restrict__ flag, const float* __restrict__ x,
    const float* __restrict__ cw, const float* __restrict__ cb,
    unsigned int* __restrict__ cur1) {
  if (flag[0]) return;
  __shared__ float w_s[CO_ * C_ * 3];
  __shared__ float b_s[CO_];
  for (int i = threadIdx.x; i < CO_ * C_ * 3; i += blockDim.x) w_s[i] = cw[i];
  if (threadIdx.x < CO_) b_s[threadIdx.x] = cb[threadIdx.x];
  __syncthreads();
  int idx = blockIdx.x * blockDim.x + threadIdx.x;  // b*T + t
  if (idx >= B_ * T_) return;
  int b = idx / T_, t = idx % T_;
  float xin[3][C_];
#pragma unroll
  for (int k = 0; k < 3; ++k) {
    int tt = t + k - 1;
    if (tt < 0 || tt >= T_) {
#pragma unroll
      for (int c = 0; c < C_; ++c) xin[k][c] = 0.f;
    } else {
      const float* p = x + ((size_t)b * T_ + tt) * C_;
#pragma unroll
      for (int c = 0; c < C_; ++c) xin[k][c] = p[c];
    }
  }
  unsigned int bits = 0u;
  for (int oc = 0; oc < CO_; ++oc) {
    float s = b_s[oc];
    const float* wr = &w_s[oc * C_ * 3];
#pragma unroll
    for (int ic = 0; ic < C_; ++ic)
#pragma unroll
      for (int k = 0; k < 3; ++k) s = fmaf(xin[k][ic], wr[ic * 3 + k], s);
    if (s - 1.0f > 0.f) bits |= (1u << oc);
  }
  cur1[idx] = bits;
}

// ---------------- Kernel 2: honest SLSTM layer 1 (fallback only) -----------
__global__ __launch_bounds__(512, 2) void k_slstm1(
    const int* __restrict__ flag, const unsigned int* __restrict__ cur1,
    const float* __restrict__ w_ih, const float* __restrict__ w_hh,
    const float* __restrict__ b_ih, const float* __restrict__ b_hh,
    const float* __restrict__ thr_p, unsigned long long* __restrict__ spk_bits,
    unsigned int* __restrict__ count) {
  if (flag[0]) return;  // fast path: spikes provably zero; count stays 0
  const int g = threadIdx.x;
  const int t0 = blockIdx.x * 2;
  const float thr = thr_p[0];
  float wih[32], whh[H_];
#pragma unroll
  for (int k = 0; k < 32; ++k) wih[k] = w_ih[g * 32 + k];
#pragma unroll
  for (int k = 0; k < H_; ++k) whh[k] = w_hh[g * H_ + k];
  const float bias = b_ih[g] + b_hh[g];
  __shared__ float mem_s[2][H_];
  __shared__ float gate_s[2][G_];
  float syn = 0.f;
  int cnt = 0;
  if (g < 256) mem_s[g >> 7][g & 127] = 0.f;
  __syncthreads();
  for (int b = 0; b < B_; ++b) {
    unsigned int bits0 = cur1[b * T_ + t0];
    unsigned int bits1 = cur1[b * T_ + t0 + 1];
    float s0 = bias, s1 = bias;
#pragma unroll
    for (int k = 0; k < 32; ++k) {
      s0 += ((bits0 >> k) & 1u) ? wih[k] : 0.f;
      s1 += ((bits1 >> k) & 1u) ? wih[k] : 0.f;
    }
#pragma unroll
    for (int k = 0; k < H_; ++k) {
      s0 = fmaf(whh[k], mem_s[0][k], s0);
      s1 = fmaf(whh[k], mem_s[1][k], s1);
    }
    gate_s[0][g] = s0;
    gate_s[1][g] = s1;
    __syncthreads();
    if (g < 256) {
      const int r = g >> 7, h = g & 127;
      float gi = gate_s[r][h];
      float gf = gate_s[r][h + 128];
      float gg = gate_s[r][h + 256];
      float go = gate_s[r][h + 384];
      float ii = 1.f / (1.f + expf(-gi));
      float ff = 1.f / (1.f + expf(-gf));
      float gt = tanhf(gg);
      float oo = 1.f / (1.f + expf(-go));
      float memp = mem_s[r][h];
      float rst = (memp - thr > 0.f) ? thr : 0.f;
      syn = ff * syn + ii * gt;
      float mm = oo * tanhf(syn) - rst;
      mem_s[r][h] = mm;
      bool spk = (mm - thr) > 0.f;
      cnt += spk ? 1 : 0;
      unsigned long long m = __ballot(spk);
      if ((g & 63) == 0)
        spk_bits[((size_t)b * T_ + t0 + r) * 2 + ((h >> 6) & 1)] = m;
    }
    __syncthreads();
  }
  if (g < 256) atomicAdd(&count[g & 127], (unsigned int)cnt);
}

// ---------------- Kernel 3: BN params from spike counts --------------------
// Runs in BOTH paths (fast path: count==0 -> c = beta exactly).
__global__ void k_bnprep(const unsigned int* __restrict__ count,
                         const float* __restrict__ gamma,
                         const float* __restrict__ beta,
                         float* __restrict__ a, float* __restrict__ c) {
  int h = threadIdx.x;
  if (h >= H_) return;
  const float inv_n = 1.f / (float)(B_ * T_);
  float mu = (float)count[h] * inv_n;
  float var = mu * (1.f - mu);
  float ai = gamma[h] / sqrtf(var + 1e-5f);
  a[h] = ai;
  c[h] = beta[h] - mu * ai;
}

// ---------------- Kernel 4: fold BN into layer-2 weights (cg both paths) ---
__global__ void k_fold(const int* __restrict__ flag,
                       const float* __restrict__ w_ih2,
                       const float* __restrict__ b_ih2,
                       const float* __restrict__ b_hh2,
                       const float* __restrict__ a, const float* __restrict__ c,
                       float* __restrict__ W2p, float* __restrict__ cg) {
  int gi = blockIdx.x * blockDim.x + threadIdx.x;  // 0..511
  if (gi >= G_) return;
  const int fl = flag[0];
  float s = b_ih2[gi] + b_hh2[gi];
  for (int h = 0; h < H_; ++h) {
    float w = w_ih2[gi * H_ + h];
    if (!fl) W2p[h * G_ + gi] = w * a[h];  // fallback-only matrix
    s = fmaf(w, c[h], s);
  }
  cg[gi] = s;
}

// ---------------- Kernel 5: honest SLSTM layer 2 (fallback only) -----------
__global__ __launch_bounds__(512, 2) void k_slstm2(
    const int* __restrict__ flag, const unsigned long long* __restrict__ spk_bits,
    const float* __restrict__ w_hh, const float* __restrict__ W2p,
    const float* __restrict__ cg, const float* __restrict__ thr_p,
    float* __restrict__ acc_out) {
  if (flag[0]) return;  // fast path handled by k_traj
  const int g = threadIdx.x;
  const int t0 = blockIdx.x * 2;
  const float thr = thr_p[0];
  float whh[H_];
#pragma unroll
  for (int k = 0; k < H_; ++k) whh[k] = w_hh[g * H_ + k];
  const float bias = cg[g];
  __shared__ float mem_s[2][H_];
  __shared__ float gate_s[2][G_];
  float syn = 0.f, accv = 0.f;
  if (g < 256) mem_s[g >> 7][g & 127] = 0.f;
  __syncthreads();
  for (int b = 0; b < B_; ++b) {
    unsigned long long m00 = spk_bits[((size_t)b * T_ + t0) * 2 + 0];
    unsigned long long m01 = spk_bits[((size_t)b * T_ + t0) * 2 + 1];
    unsigned long long m10 = spk_bits[((size_t)b * T_ + t0 + 1) * 2 + 0];
    unsigned long long m11 = spk_bits[((size_t)b * T_ + t0 + 1) * 2 + 1];
    float s0 = bias, s1 = bias;
    while (m00) { int h = __ffsll(m00) - 1; m00 &= m00 - 1; s0 += W2p[h * G_ + g]; }
    while (m01) { int h = __ffsll(m01) - 1; m01 &= m01 - 1; s0 += W2p[(h + 64) * G_ + g]; }
    while (m10) { int h = __ffsll(m10) - 1; m10 &= m10 - 1; s1 += W2p[h * G_ + g]; }
    while (m11) { int h = __ffsll(m11) - 1; m11 &= m11 - 1; s1 += W2p[(h + 64) * G_ + g]; }
#pragma unroll
    for (int k = 0; k < H_; ++k) {
      s0 = fmaf(whh[k], mem_s[0][k], s0);
      s1 = fmaf(whh[k], mem_s[1][k], s1);
    }
    gate_s[0][g] = s0;
    gate_s[1][g] = s1;
    __syncthreads();
    if (g < 256) {
      const int r = g >> 7, h = g & 127;
      float gi = gate_s[r][h];
      float gf = gate_s[r][h + 128];
      float gg = gate_s[r][h + 256];
      float go = gate_s[r][h + 384];
      float ii = 1.f / (1.f + expf(-gi));
      float ff = 1.f / (1.f + expf(-gf));
      float gt = tanhf(gg);
      float oo = 1.f / (1.f + expf(-go));
      float memp = mem_s[r][h];
      float rst = (memp - thr > 0.f) ? thr : 0.f;
      syn = ff * syn + ii * gt;
      float mm = oo * tanhf(syn) - rst;
      mem_s[r][h] = mm;
      accv += mm;
    }
    __syncthreads();
  }
  if (g < 256) acc_out[(size_t)(t0 + (g >> 7)) * H_ + (g & 127)] = accv;
}

// ---------------- Kernel 5b: FAST layer 2 — single shared trajectory -------
// thr1>=1 -> layer-2 input = beta every row/step -> ONE 256-step trajectory.
// 1024 threads: thread i owns gate g=i&511, half hf=i>>9 (WAVE-UNIFORM).
// Per wave per step: ONE ds_read_b32 (own mem element), then v_readlane
// broadcasts to SGPR and v_fma uses the SGPR operand -> zero LDS broadcast
// traffic. Halves combine via part_s. Weights: 16 named float4, pinned.
#define PIN4(v) asm volatile("" : "+v"(v.x), "+v"(v.y), "+v"(v.z), "+v"(v.w))

#define RL4(K, W)                                                            \
  {                                                                          \
    float mk;                                                                \
    mk = __uint_as_float(__builtin_amdgcn_readlane(vm, (K)));                \
    a0 = fmaf((W).x, mk, a0);                                                \
    mk = __uint_as_float(__builtin_amdgcn_readlane(vm, (K) + 1));            \
    a1 = fmaf((W).y, mk, a1);                                                \
    mk = __uint_as_float(__builtin_amdgcn_readlane(vm, (K) + 2));            \
    a2 = fmaf((W).z, mk, a2);                                                \
    mk = __uint_as_float(__builtin_amdgcn_readlane(vm, (K) + 3));            \
    a3 = fmaf((W).w, mk, a3);                                                \
  }

__global__ __launch_bounds__(1024)
__attribute__((amdgpu_waves_per_eu(4, 4))) void k_traj(
    const int* __restrict__ flag, const float* __restrict__ w_hh,
    const float* __restrict__ cg, const float* __restrict__ thr_p,
    const float* __restrict__ fc_w, const float* __restrict__ fc_b,
    float* __restrict__ out) {
  if (!flag[0]) return;
  const int i = threadIdx.x;
  const int g = i & 511;      // gate
  const int hf = i >> 9;      // half: waves 0-7 -> 0, waves 8-15 -> 1
  const int lane = i & 63;
  const float thr = thr_p[0];

  const float* wr = w_hh + (size_t)g * H_ + hf * 64;
  float4 w0 = *(const float4*)(wr);
  float4 w1 = *(const float4*)(wr + 4);
  float4 w2 = *(const float4*)(wr + 8);
  float4 w3 = *(const float4*)(wr + 12);
  float4 w4 = *(const float4*)(wr + 16);
  float4 w5 = *(const float4*)(wr + 20);
  float4 w6 = *(const float4*)(wr + 24);
  float4 w7 = *(const float4*)(wr + 28);
  float4 w8 = *(const float4*)(wr + 32);
  float4 w9 = *(const float4*)(wr + 36);
  float4 wA = *(const float4*)(wr + 40);
  float4 wB = *(const float4*)(wr + 44);
  float4 wC = *(const float4*)(wr + 48);
  float4 wD = *(const float4*)(wr + 52);
  float4 wE = *(const float4*)(wr + 56);
  float4 wF = *(const float4*)(wr + 60);
  float bias = hf ? 0.f : cg[g];

  __shared__ float mem_s[H_];
  __shared__ float part_s[2][G_];
  __shared__ float red_s[H_ + 8];
  float syn = 0.f, accm = 0.f;
  if (i < H_) mem_s[i] = 0.f;
  __syncthreads();

  for (int b = 0; b < B_; ++b) {
    PIN4(w0); PIN4(w1); PIN4(w2); PIN4(w3);
    PIN4(w4); PIN4(w5); PIN4(w6); PIN4(w7);
    PIN4(w8); PIN4(w9); PIN4(wA); PIN4(wB);
    PIN4(wC); PIN4(wD); PIN4(wE); PIN4(wF);
    asm volatile("" : "+v"(bias));
    // phase 1: one LDS read per lane, then register broadcast via readlane
    const int vm = __float_as_int(mem_s[(hf << 6) + lane]);
    float a0 = bias, a1 = 0.f, a2 = 0.f, a3 = 0.f;
    RL4(0, w0)  RL4(4, w1)  RL4(8, w2)  RL4(12, w3)
    RL4(16, w4) RL4(20, w5) RL4(24, w6) RL4(28, w7)
    RL4(32, w8) RL4(36, w9) RL4(40, wA) RL4(44, wB)
    RL4(48, wC) RL4(52, wD) RL4(56, wE) RL4(60, wF)
    part_s[hf][g] = (a0 + a1) + (a2 + a3);
    __syncthreads();
    // phase 2: 512 threads, one transcendental each; quad-shfl gather
    if (i < 512) {
      const int h = i >> 2, r = i & 3;
      const int idx = h + (r << 7);
      float xg = part_s[0][idx] + part_s[1][idx];
      float act = (r == 2) ? tanh_fast(xg) : sigm_fast(xg);
      const int base = (i & 63) & ~3;
      float af = __shfl(act, base + 1);
      float ag = __shfl(act, base + 2);
      float ao = __shfl(act, base + 3);
      if (r == 0) {
        float memp = mem_s[h];
        float rst = (memp - thr > 0.f) ? thr : 0.f;  // honest (thr2 runtime)
        syn = af * syn + act * ag;
        float mm = ao * tanh_fast(syn) - rst;
        mem_s[h] = mm;
        accm += mm;
      }
    }
    __syncthreads();
  }
  // mean over steps -> FC (8 outputs) -> broadcast to all 512 rows
  if (i < 512 && (i & 3) == 0) red_s[i >> 2] = accm * (1.f / 256.f);
  __syncthreads();
  if (i < 8) {
    float s = fc_b[i];
    const float* fw = fc_w + i * H_;
    for (int h = 0; h < H_; ++h) s = fmaf(red_s[h], fw[h], s);
    red_s[H_ + i] = s;
  }
  __syncthreads();
  for (int idx = i; idx < T_ * 8; idx += 1024) out[idx] = red_s[H_ + (idx & 7)];
}

// ---------------- Kernel 6: final mean + FC (fallback only) ----------------
__global__ void k_out(const int* __restrict__ flag, const float* __restrict__ accv,
                      const float* __restrict__ fc_w,
                      const float* __restrict__ fc_b, float* __restrict__ out) {
  if (flag[0]) return;
  int idx = blockIdx.x * blockDim.x + threadIdx.x;  // t*8+n
  if (idx >= T_ * 8) return;
  int t = idx >> 3, n = idx & 7;
  float s = fc_b[n];
  for (int h = 0; h < H_; ++h)
    s = fmaf(accv[t * H_ + h] * (1.f / 256.f), fc_w[n * H_ + h], s);
  out[idx] = s;
}

extern "C" void kernel_launch(void* const* d_in, const int* in_sizes, int n_in,
                              void* d_out, int out_size, void* d_ws, size_t ws_size,
                              hipStream_t stream) {
  const float* x       = (const float*)d_in[0];
  const float* conv_w  = (const float*)d_in[1];
  const float* conv_b  = (const float*)d_in[2];
  const float* w_ih1   = (const float*)d_in[3];
  const float* w_hh1   = (const float*)d_in[4];
  const float* b_ih1   = (const float*)d_in[5];
  const float* b_hh1   = (const float*)d_in[6];
  const float* thr1    = (const float*)d_in[7];
  const float* w_ih2   = (const float*)d_in[8];
  const float* w_hh2   = (const float*)d_in[9];
  const float* b_ih2   = (const float*)d_in[10];
  const float* b_hh2   = (const float*)d_in[11];
  const float* thr2    = (const float*)d_in[12];
  const float* bn_g    = (const float*)d_in[13];
  const float* bn_b    = (const float*)d_in[14];
  const float* fc_w    = (const float*)d_in[15];
  const float* fc_b    = (const float*)d_in[16];
  float* out = (float*)d_out;

  char* ws = (char*)d_ws;
  unsigned int* cur1       = (unsigned int*)(ws);                    // 512 KB
  unsigned long long* spk  = (unsigned long long*)(ws + (512 << 10));// 2 MB
  unsigned int* count      = (unsigned int*)(ws + (2560 << 10));     // 512 B
  float* a                 = (float*)(ws + (2561 << 10));            // 512 B
  float* c                 = (float*)(ws + (2562 << 10));            // 512 B
  float* cg                = (float*)(ws + (2563 << 10));            // 2 KB
  float* W2p               = (float*)(ws + (2566 << 10));            // 256 KB
  float* accv              = (float*)(ws + (2822 << 10));            // 256 KB
  int* flag                = (int*)(ws + (3078 << 10));              // 4 B

  hipMemsetAsync(count, 0, H_ * sizeof(unsigned int), stream);
  k_flag<<<1, 64, 0, stream>>>(thr1, flag);
  k_conv_spike<<<(B_ * T_ + 255) / 256, 256, 0, stream>>>(flag, x, conv_w, conv_b, cur1);
  k_slstm1<<<T_ / 2, 512, 0, stream>>>(flag, cur1, w_ih1, w_hh1, b_ih1, b_hh1,
                                       thr1, spk, count);
  k_bnprep<<<1, 128, 0, stream>>>(count, bn_g, bn_b, a, c);
  k_fold<<<1, 512, 0, stream>>>(flag, w_ih2, b_ih2, b_hh2, a, c, W2p, cg);
  k_slstm2<<<T_ / 2, 512, 0, stream>>>(flag, spk, w_hh2, W2p, cg, thr2, accv);
  k_traj<<<1, 1024, 0, stream>>>(flag, w_hh2, cg, thr2, fc_w, fc_b, out);
  k_out<<<(T_ * 8 + 255) / 256, 256, 0, stream>>>(flag, accv, fc_w, fc_b, out);
}